// Round 23
// baseline (870.529 us; speedup 1.0000x reference)
//
#include <hip/hip_runtime.h>
#include <hip/hip_bf16.h>

// ---------------------------------------------------------------------------
// RNNModel (MDN-RNN). Segment algorithm (R9-R22). R23: consolidation round.
//   - lstm_seg_k, seg_build_k: byte-identical to passing R22 (605us floor:
//     burst-gather + 15 global barriers; 6 structural probes all <=4%).
//   - out_gemm N=160 (grid 128x12): halves A-passes (12x vs 24x re-read of
//     hs2 rows); 10 B-subtiles + done row as subtile 10 (rows 161-175 zero).
//     logmix lse in two 80-col phases reusing ep[128][84] (5-groups never
//     cross an 80-col boundary).
//   - prep_k merges cvt_z + cvt_wout + zero_hs_tail (one launch).
// Layout (R20): 256 blocks = 128 col-groups x 2 slot-halves; group g owns
// 8 h-cols = 32 gate rows; 16B gather feeds 2 N-subtiles (8 MFMA/kt).
// hs2 [128][16384][2u64]; c_all 32B/slot block-private; ladder h-exchange
// (region_s at loff[s], write-once agent atomics, plain clamped gathers).
// ---------------------------------------------------------------------------

typedef float f4 __attribute__((ext_vector_type(4)));
typedef short s8 __attribute__((ext_vector_type(8)));
typedef unsigned short us8v __attribute__((ext_vector_type(8)));
typedef unsigned short us4v __attribute__((ext_vector_type(4)));
typedef unsigned long long u64;
typedef unsigned u32;

#define DEV __device__ __forceinline__

DEV unsigned short f2b(float f) {          // fp32 -> bf16 RNE
  unsigned u = __float_as_uint(f);
  return (unsigned short)((u + 0x7FFFu + ((u >> 16) & 1u)) >> 16);
}
DEV float b2f(unsigned short s) { return __uint_as_float(((unsigned)s) << 16); }

DEV f4 MFMA(s8 a, s8 b, f4 c) {
  return __builtin_amdgcn_mfma_f32_16x16x32_bf16(a, b, c, 0, 0, 0);
}
DEV s8 LD8(const unsigned short* p) { return *reinterpret_cast<const s8*>(p); }

DEV u32 AL32(const u32* p) {
  return __hip_atomic_load(p, __ATOMIC_RELAXED, __HIP_MEMORY_SCOPE_AGENT);
}
DEV void AS(u64* p, u64 v) {
  __hip_atomic_store(p, v, __ATOMIC_RELAXED, __HIP_MEMORY_SCOPE_AGENT);
}

DEV float sigf(float x) {
  float e = __builtin_amdgcn_exp2f(x * -1.44269504f);
  return __builtin_amdgcn_rcpf(1.f + e);
}
DEV float tanhf_fast(float x) {
  float e = __builtin_amdgcn_exp2f(x * 2.88539008f);
  return 1.f - 2.f * __builtin_amdgcn_rcpf(e + 1.f);
}

// ---- d_ws layout (bytes) ----
static constexpr size_t WS_GCNT = 0;
static constexpr size_t WS_NACT = 2048;
static constexpr size_t WS_HDR  = 4096;
static constexpr size_t WS_META = 4352;
static constexpr size_t WS_LOFF = 69888;
static constexpr size_t WS_TMP  = 131072;
static constexpr size_t WS_ZT   = 131072;
static constexpr size_t WS_WOUT = 4325376;
static constexpr size_t WS_HS2  = 8261632;  // hs2 [128][16384][2 u64] (32MB)
static constexpr size_t WS_END  = 41816064;
// ---- d_out scratch ----
static constexpr size_t DO_CALL = 35651584; // c_all [256][8192][4 u64]

// ---------------------------------------------------------------------------
// prep_k: fused cvt_z (blocks 0..2047), cvt_wout (2048..3969),
// zero_hs_tail (3970..4001).
__global__ void prep_k(const float* __restrict__ z, unsigned short* __restrict__ zt,
                       const float* __restrict__ W, unsigned short* __restrict__ wout16,
                       u64* __restrict__ hs2) {
  const int bid = blockIdx.x;
  const int tid = threadIdx.x;
  if (bid < 2048) {                       // z: 524288 float4 units exact
    int i = bid * 256 + tid;
    const float4 v = reinterpret_cast<const float4*>(z)[i];
    us4v u; u[0] = f2b(v.x); u[1] = f2b(v.y); u[2] = f2b(v.z); u[3] = f2b(v.w);
    reinterpret_cast<us4v*>(zt)[i] = u;
  } else if (bid < 3970) {                // wout: 491776 float4 units
    int i = (bid - 2048) * 256 + tid;
    if (i < 491776) {
      const float4 v = reinterpret_cast<const float4*>(W)[i];
      us4v u; u[0] = f2b(v.x); u[1] = f2b(v.y); u[2] = f2b(v.z); u[3] = f2b(v.w);
      reinterpret_cast<us4v*>(wout16)[i] = u;
    }
  } else {                                // hs2 tail rows 16352..16383
    int i = (bid - 3970) * 256 + tid;
    if (i < 8192) {
      int region = i >> 6, rr = (i & 63) >> 1, hf = i & 1;
      hs2[((size_t)region * 16384 + 16352 + rr) * 2 + hf] = 0ull;
    }
  }
}

// ---------------------------------------------------------------------------
__global__ __launch_bounds__(256) void seg_build_k(
    const int* __restrict__ dones, u32* __restrict__ tmp,
    u32* __restrict__ meta, u32* __restrict__ nact, u32* __restrict__ hdr,
    u32* __restrict__ loff) {
  __shared__ u32 hist[512];
  __shared__ u32 cur[512];
  __shared__ u32 scnt[32];
  const int tid = threadIdx.x;
  for (int i = tid; i < 512; i += 256) hist[i] = 0;
  __syncthreads();
  if (tid < 32) {
    int b = tid, cnt = 0, t0 = 0;
    for (int t = 1; t <= 511; ++t) {
      bool brk = (t == 511) || (dones[b * 512 + t - 1] != 0);
      if (brk) {
        int len = t - t0;
        tmp[b * 511 + cnt] = ((u32)t0 << 16) | (u32)len;
        atomicAdd(&hist[len], 1u);
        ++cnt; t0 = t;
      }
    }
    scnt[b] = (u32)cnt;
  }
  __syncthreads();
  if (tid == 0) {
    u32 acc = 0; int ml = 0;
    for (int L = 511; L >= 0; --L) {
      cur[L] = acc; nact[L] = acc;
      if (hist[L] && !ml) ml = L;
      acc += hist[L];
    }
    hdr[0] = acc; hdr[1] = (u32)ml;
    u32 off = 0; loff[0] = 0;
    for (int s2 = 1; s2 <= ml; ++s2) { loff[s2] = off; off += nact[s2]; }
  }
  __syncthreads();
  if (tid < 32) {
    int b = tid; u32 c = scnt[b];
    for (u32 i = 0; i < c; ++i) {
      u32 e = tmp[b * 511 + i];
      u32 len = e & 0xFFFFu, t0 = e >> 16;
      u32 slot = atomicAdd(&cur[len], 1u);
      meta[slot] = ((u32)b << 20) | (t0 << 10) | len;
    }
  }
}

// ---------------------------------------------------------------------------
// Segment-batched LSTM (R20/R22 verbatim). grid=256 = 128 col-groups x 2
// halves; block=512 (8 waves). Lane owns one slot (8 cols). 64-slot tiles.
__global__ __launch_bounds__(512, 1) void lstm_seg_k(
    const float* __restrict__ Whh, const float* __restrict__ Wih,
    const float* __restrict__ embed, const float* __restrict__ bih,
    const float* __restrict__ bhh, const int* __restrict__ actions,
    const unsigned short* __restrict__ zt, const u32* __restrict__ meta,
    const u32* __restrict__ nact, const u32* __restrict__ hdr,
    const u32* __restrict__ loff, u64* __restrict__ hsl,
    u64* __restrict__ c_all, u64* __restrict__ hs2,
    u32* __restrict__ gcnt) {
  const int blk = blockIdx.x;
  const int g = blk >> 1;                 // col-group 0..127
  const int half = blk & 1;               // slot-tile parity
  const int tid = threadIdx.x;
  const int lane = tid & 63;
  const int w = tid >> 6;                 // wave 0..7
  const int ln = lane & 15, lk = lane >> 4;

  __shared__ alignas(16) unsigned short whh_sw[32 * 2 * 64 * 8];  // 64 KB
  __shared__ alignas(16) unsigned short wz_sw[4 * 2 * 64 * 8];    // 8 KB
  __shared__ float abias[18][32];
  __shared__ float red[8][64][33];        // wave-private transpose 67.6KB

  for (int i = tid; i < 32768; i += 512) {
    int j = i & 7, L = (i >> 3) & 63, nt = (i >> 9) & 1, kt = i >> 10;
    int n = nt * 16 + (L & 15);           // packed gate idx 0..31
    int grow = (n >> 3) * 1024 + g * 8 + (n & 7);
    int k = kt * 32 + ((L >> 4) << 3) + j;
    whh_sw[i] = f2b(Whh[grow * 1024 + k]);
  }
  for (int i = tid; i < 4096; i += 512) {
    int j = i & 7, L = (i >> 3) & 63, nt = (i >> 9) & 1, kz = i >> 10;
    int n = nt * 16 + (L & 15);
    int grow = (n >> 3) * 1024 + g * 8 + (n & 7);
    int k = kz * 32 + ((L >> 4) << 3) + j;
    wz_sw[i] = f2b(Wih[grow * 144 + k]);
  }
  for (int i = tid; i < 18 * 32; i += 512) {
    int a = i >> 5, n = i & 31;
    int grow = (n >> 3) * 1024 + g * 8 + (n & 7);
    float s = bih[grow] + bhh[grow];
    for (int j = 0; j < 16; ++j) s += embed[a * 16 + j] * Wih[grow * 144 + 128 + j];
    abias[a][n] = s;
  }
  __syncthreads();

  const int maxlen = (int)hdr[1];

  for (int s = 0; s < maxlen; ++s) {
    const u32 N = nact[s];
    const int ntiles = (int)((N + 63) >> 6);
    const u64* hread = hsl + (size_t)loff[s] * 256;
    u64* hwrite = hsl + (size_t)loff[s + 1] * 256;

    for (int tile = half + 2 * w; tile < ntiles; tile += 16) {
      const u32 sb = (u32)tile << 6;
      const u32 slot = sb + (u32)lane;
      const bool valid = slot < N;
      const u32 m = valid ? meta[slot] : 0u;
      const u32 b = m >> 20, t0 = (m >> 10) & 1023u, L = m & 1023u;
      const int zrow = (int)(b * 512u + t0 + (u32)s);
      const int orow = (int)(b * 511u + t0 + (u32)s);
      const u32 act = valid ? (u32)actions[zrow] : 0u;
      u64 cq[4] = {0, 0, 0, 0};
      if (s && valid) {
        const u64* cp = c_all + ((size_t)blk << 15) + ((size_t)slot << 2);
        cq[0] = cp[0]; cq[1] = cp[1]; cq[2] = cp[2]; cq[3] = cp[3];
      }
      int zr[4];
#pragma unroll
      for (int q = 0; q < 4; ++q) zr[q] = __shfl(zrow, ln + 16 * q, 64);

      f4 a00 = {0,0,0,0}, a01 = {0,0,0,0}, a10 = {0,0,0,0}, a11 = {0,0,0,0};
      f4 a20 = {0,0,0,0}, a21 = {0,0,0,0}, a30 = {0,0,0,0}, a31 = {0,0,0,0};
#pragma unroll
      for (int kz = 0; kz < 4; ++kz) {     // z contribution (K=128)
        s8 b0 = LD8(wz_sw + (((kz * 2 + 0) * 64 + lane) << 3));
        s8 b1 = LD8(wz_sw + (((kz * 2 + 1) * 64 + lane) << 3));
        s8 f0 = LD8(zt + (size_t)zr[0] * 128 + kz * 32 + (lk << 3));
        s8 f1 = LD8(zt + (size_t)zr[1] * 128 + kz * 32 + (lk << 3));
        s8 f2 = LD8(zt + (size_t)zr[2] * 128 + kz * 32 + (lk << 3));
        s8 f3 = LD8(zt + (size_t)zr[3] * 128 + kz * 32 + (lk << 3));
        a00 = MFMA(f0, b0, a00);  a01 = MFMA(f0, b1, a01);
        a10 = MFMA(f1, b0, a10);  a11 = MFMA(f1, b1, a11);
        a20 = MFMA(f2, b0, a20);  a21 = MFMA(f2, b1, a21);
        a30 = MFMA(f3, b0, a30);  a31 = MFMA(f3, b1, a31);
      }
      if (s) {  // h gather: plain coalesced 16B loads, clamped inside region
        const u32 r0c = (sb + (u32)ln      < N) ? sb + (u32)ln      : N - 1u;
        const u32 r1c = (sb + (u32)ln + 16 < N) ? sb + (u32)ln + 16 : N - 1u;
        const u32 r2c = (sb + (u32)ln + 32 < N) ? sb + (u32)ln + 32 : N - 1u;
        const u32 r3c = (sb + (u32)ln + 48 < N) ? sb + (u32)ln + 48 : N - 1u;
        const unsigned short* h0 =
            (const unsigned short*)(hread + (size_t)r0c * 256) + (lk << 3);
        const unsigned short* h1 =
            (const unsigned short*)(hread + (size_t)r1c * 256) + (lk << 3);
        const unsigned short* h2 =
            (const unsigned short*)(hread + (size_t)r2c * 256) + (lk << 3);
        const unsigned short* h3 =
            (const unsigned short*)(hread + (size_t)r3c * 256) + (lk << 3);
#pragma unroll 8
        for (int kt = 0; kt < 32; ++kt) {
          s8 b0 = LD8(whh_sw + (((kt * 2 + 0) * 64 + lane) << 3));
          s8 b1 = LD8(whh_sw + (((kt * 2 + 1) * 64 + lane) << 3));
          s8 f0 = LD8(h0 + (kt << 5));
          s8 f1 = LD8(h1 + (kt << 5));
          s8 f2 = LD8(h2 + (kt << 5));
          s8 f3 = LD8(h3 + (kt << 5));
          a00 = MFMA(f0, b0, a00);  a01 = MFMA(f0, b1, a01);
          a10 = MFMA(f1, b0, a10);  a11 = MFMA(f1, b1, a11);
          a20 = MFMA(f2, b0, a20);  a21 = MFMA(f2, b1, a21);
          a30 = MFMA(f3, b0, a30);  a31 = MFMA(f3, b1, a31);
        }
      }

      // transpose: D row = 16q + 4lk + j, col = nt*16 + ln
#pragma unroll
      for (int j = 0; j < 4; ++j) {
        red[w][(lk << 2) + j][ln]           = a00[j];
        red[w][(lk << 2) + j][16 + ln]      = a01[j];
        red[w][16 + (lk << 2) + j][ln]      = a10[j];
        red[w][16 + (lk << 2) + j][16 + ln] = a11[j];
        red[w][32 + (lk << 2) + j][ln]      = a20[j];
        red[w][32 + (lk << 2) + j][16 + ln] = a21[j];
        red[w][48 + (lk << 2) + j][ln]      = a30[j];
        red[w][48 + (lk << 2) + j][16 + ln] = a31[j];
      }
      // same-wave DS ordering
      const bool carry = valid && (L > (u32)(s + 1));
      u32 cb[8]; unsigned short hb[8];
#pragma unroll
      for (int e = 0; e < 8; ++e) {   // lane's slot, cols 0..7
        float gi = red[w][lane][e]      + abias[act][e];
        float gf = red[w][lane][8 + e]  + abias[act][8 + e];
        float gg = red[w][lane][16 + e] + abias[act][16 + e];
        float go = red[w][lane][24 + e] + abias[act][24 + e];
        const u32 cpb = (e & 1) ? (u32)(cq[e >> 1] >> 32) : (u32)cq[e >> 1];
        const float cprev = __uint_as_float(cpb);
        const float si = sigf(gi), sf = sigf(gf), so = sigf(go);
        const float cn = sf * cprev + si * tanhf_fast(gg);
        const float hn = so * tanhf_fast(cn);
        cb[e] = __float_as_uint(cn);
        hb[e] = f2b(hn);
      }
      if (carry) {   // c carry: 32B plain store
        u64* cp = c_all + ((size_t)blk << 15) + ((size_t)slot << 2);
        cp[0] = ((u64)cb[1] << 32) | (u64)cb[0];
        cp[1] = ((u64)cb[3] << 32) | (u64)cb[2];
        cp[2] = ((u64)cb[5] << 32) | (u64)cb[4];
        cp[3] = ((u64)cb[7] << 32) | (u64)cb[6];
      }
      const u64 hu0 = (u64)hb[0] | ((u64)hb[1] << 16) |
                      ((u64)hb[2] << 32) | ((u64)hb[3] << 48);
      const u64 hu1 = (u64)hb[4] | ((u64)hb[5] << 16) |
                      ((u64)hb[6] << 32) | ((u64)hb[7] << 48);
      if (valid) {
        u64* hp = hs2 + ((size_t)g * 16384 + orow) * 2;
        hp[0] = hu0; hp[1] = hu1;                      // history (plain)
        if (carry) {                                   // carry h (atomic)
          AS(hwrite + (size_t)slot * 256 + 2 * g, hu0);
          AS(hwrite + (size_t)slot * 256 + 2 * g + 1, hu1);
        }
      }
    }

    // per-wave drain, block sync, global barrier
    asm volatile("s_waitcnt vmcnt(0)" ::: "memory");
    __syncthreads();
    if (s + 1 < maxlen) {
      if (tid == 0) {
        __hip_atomic_fetch_add(gcnt + (blk >> 4) * 32, 1u,
                               __ATOMIC_RELAXED, __HIP_MEMORY_SCOPE_AGENT);
        const u32 tgt = (u32)(s + 1) * 16u;
        for (u32 spin = 0; spin < (1u << 20); ++spin) {
          u32 mn = 0xFFFFFFFFu;
#pragma unroll
          for (int gg2 = 0; gg2 < 16; ++gg2) {
            u32 v = AL32(gcnt + gg2 * 32);
            mn = (v < mn) ? v : mn;
          }
          if (mn >= tgt) break;
          __builtin_amdgcn_s_sleep(1);
        }
      }
      __syncthreads();
    }
  }
}

// ---------------------------------------------------------------------------
// out = hs @ W_out^T (+bias). R23: N=160 (grid 128x12), M=128. nblk==11 also
// computes done_p (W_out row 1920 as subtile 10, rows 161-175 zero-padded).
// logmix (nblk 0..3): lse in two 80-col phases reusing ep[128][84].
__global__ __launch_bounds__(256, 2) void out_gemm_k(
    const u64* __restrict__ hs2, const unsigned short* __restrict__ wout,
    const float* __restrict__ b_out, float* __restrict__ out) {
  const int mblk = blockIdx.x, nblk = blockIdx.y;
  const int tid = threadIdx.x, lane = tid & 63, w = tid >> 6;
  const int ln = lane & 15, lk = lane >> 4;
  __shared__ alignas(16) unsigned char smraw[47872];
  unsigned short* bsm = (unsigned short*)smraw;  // [176][136] bf16 B-chunk
  float* ep = (float*)smraw;                     // [128][84] f32 lse tile
  const bool last = (nblk == 11);

  if (last) {  // zero pad rows 161..175 once
    for (int i = tid; i < 15 * 136; i += 256) bsm[161 * 136 + i] = 0;
  }
  __syncthreads();

  const int r0 = mblk * 128 + w * 16;    // lower subtile; upper = r0+64
  f4 accA[10], accB[10];
#pragma unroll
  for (int s = 0; s < 10; ++s) {
    accA[s] = (f4){0.f, 0.f, 0.f, 0.f};
    accB[s] = (f4){0.f, 0.f, 0.f, 0.f};
  }
  f4 acc5A = {0.f, 0.f, 0.f, 0.f}, acc5B = {0.f, 0.f, 0.f, 0.f};

  for (int kc = 0; kc < 8; ++kc) {  // K chunks of 128
#pragma unroll
    for (int ii = 0; ii < 10; ++ii) {          // 2560 us8 chunks exact
      int i = tid + ii * 256;
      int n = i >> 4, k16 = i & 15;
      us8v v = *reinterpret_cast<const us8v*>(
          wout + (size_t)(nblk * 160 + n) * 1024 + kc * 128 + (k16 << 3));
      *reinterpret_cast<us8v*>(bsm + n * 136 + (k16 << 3)) = v;
    }
    if (last && tid < 16) {                    // row 160 = wout row 1920
      us8v v = *reinterpret_cast<const us8v*>(
          wout + (size_t)1920 * 1024 + kc * 128 + (tid << 3));
      *reinterpret_cast<us8v*>(bsm + 160 * 136 + (tid << 3)) = v;
    }
    __syncthreads();
#pragma unroll
    for (int ks = 0; ks < 4; ++ks) {
      const int k0 = kc * 128 + ks * 32 + (lk << 3);
      s8 aLo = *reinterpret_cast<const s8*>(
          hs2 + ((size_t)(k0 >> 3) * 16384 + r0 + ln) * 2);
      s8 aHi = *reinterpret_cast<const s8*>(
          hs2 + ((size_t)(k0 >> 3) * 16384 + r0 + 64 + ln) * 2);
#pragma unroll
      for (int s = 0; s < 10; ++s) {
        s8 b = LD8(bsm + (s * 16 + ln) * 136 + ks * 32 + (lk << 3));
        accA[s] = MFMA(aLo, b, accA[s]);
        accB[s] = MFMA(aHi, b, accB[s]);
      }
      if (last) {
        s8 b6 = LD8(bsm + ((160 + ln) * 136) + ks * 32 + (lk << 3));
        acc5A = MFMA(aLo, b6, acc5A);
        acc5B = MFMA(aHi, b6, acc5B);
      }
    }
    __syncthreads();
  }

  const int T = nblk >> 2;  // 0 logmix, 1 mu, 2 logstd
  if (T) {
    float* base = out + (size_t)10465280 * T;
    const int lc0 = (nblk & 3) * 160;
#pragma unroll
    for (int s = 0; s < 10; ++s) {
      const int lc = lc0 + s * 16 + ln;
      const float bias = b_out[T * 640 + lc];
#pragma unroll
      for (int j = 0; j < 4; ++j) {
        const int rowA = r0 + (lk << 2) + j;
        const int rowB = rowA + 64;
        if (rowA < 16352) base[(size_t)rowA * 640 + lc] = accA[s][j] + bias;
        if (rowB < 16352) base[(size_t)rowB * 640 + lc] = accB[s][j] + bias;
      }
    }
    if (last && ln == 0) {     // done_p: col 0 of subtile 10
      const float bias = b_out[1920];
#pragma unroll
      for (int j = 0; j < 4; ++j) {
        const int rowA = r0 + (lk << 2) + j;
        const int rowB = rowA + 64;
        if (rowA < 16352) out[31395840 + rowA] = acc5A[j] + bias;
        if (rowB < 16352) out[31395840 + rowB] = acc5B[j] + bias;
      }
    }
  } else {  // logmix: two 80-col lse phases (5-groups stay intra-phase)
#pragma unroll
    for (int ph = 0; ph < 2; ++ph) {
      __syncthreads();   // ep free (bsm dead after K loop / prev phase done)
#pragma unroll
      for (int sl = 0; sl < 5; ++sl) {
        const int s = ph * 5 + sl;
        const float bias = b_out[nblk * 160 + s * 16 + ln];
#pragma unroll
        for (int j = 0; j < 4; ++j) {
          ep[(w * 16 + (lk << 2) + j) * 84 + sl * 16 + ln]      = accA[s][j] + bias;
          ep[(64 + w * 16 + (lk << 2) + j) * 84 + sl * 16 + ln] = accB[s][j] + bias;
        }
      }
      __syncthreads();
      for (int task = tid; task < 2048; task += 256) {
        const int rr = task >> 4, grp = task & 15;
        const int row = mblk * 128 + rr;
        const float* e = ep + rr * 84 + grp * 5;
        float v0 = e[0], v1 = e[1], v2 = e[2], v3 = e[3], v4 = e[4];
        float mx = fmaxf(fmaxf(fmaxf(v0, v1), fmaxf(v2, v3)), v4);
        float ssum = expf(v0 - mx) + expf(v1 - mx) + expf(v2 - mx) +
                     expf(v3 - mx) + expf(v4 - mx);
        float lse = mx + logf(ssum);
        if (row < 16352) {
          float* o = out + (size_t)row * 640 + nblk * 160 + ph * 80 + grp * 5;
          o[0] = v0 - lse; o[1] = v1 - lse; o[2] = v2 - lse;
          o[3] = v3 - lse; o[4] = v4 - lse;
        }
      }
    }
  }
}

// ---------------------------------------------------------------------------
extern "C" void kernel_launch(void* const* d_in, const int* in_sizes, int n_in,
                              void* d_out, int out_size, void* d_ws, size_t ws_size,
                              hipStream_t stream) {
  const float* z       = (const float*)d_in[0];
  const int*   actions = (const int*)d_in[1];
  const int*   dones   = (const int*)d_in[2];
  const float* embed   = (const float*)d_in[3];
  const float* Wih     = (const float*)d_in[4];
  const float* Whh     = (const float*)d_in[5];
  const float* bih     = (const float*)d_in[6];
  const float* bhh     = (const float*)d_in[7];
  const float* Wout    = (const float*)d_in[8];
  const float* bout    = (const float*)d_in[9];
  float* out = (float*)d_out;

  if (ws_size < WS_END) return;

  char* ws = (char*)d_ws;
  u32* gcnt              = (u32*)(ws + WS_GCNT);
  u32* nact              = (u32*)(ws + WS_NACT);
  u32* hdr               = (u32*)(ws + WS_HDR);
  u32* metaA             = (u32*)(ws + WS_META);
  u32* loff              = (u32*)(ws + WS_LOFF);
  u32* tmp               = (u32*)(ws + WS_TMP);
  unsigned short* zt     = (unsigned short*)(ws + WS_ZT);
  unsigned short* wout16 = (unsigned short*)(ws + WS_WOUT);
  u64* hs2               = (u64*)(ws + WS_HS2);
  u64* hsl   = (u64*)d_out;                          // ladder <= 33.4MB
  u64* call  = (u64*)((char*)d_out + DO_CALL);       // 64MB c-state

  hipMemsetAsync(d_ws, 0, 2048, stream);  // barrier counters only

  seg_build_k<<<1, 256, 0, stream>>>(dones, tmp, metaA, nact, hdr, loff);
  prep_k<<<4002, 256, 0, stream>>>(z, zt, Wout, wout16, hs2);
  lstm_seg_k<<<256, 512, 0, stream>>>(Whh, Wih, embed, bih, bhh, actions,
                                      zt, metaA, nact, hdr, loff, hsl, call,
                                      hs2, gcnt);
  out_gemm_k<<<dim3(128, 12), 256, 0, stream>>>(hs2, wout16, bout, out);
}

// Round 24
// 854.905 us; speedup vs baseline: 1.0183x; 1.0183x over previous
//
#include <hip/hip_runtime.h>
#include <hip/hip_bf16.h>

// ---------------------------------------------------------------------------
// RNNModel (MDN-RNN). R24 = best-of composition:
//   lstm_seg_k + seg_build_k: R20/R22 verbatim (605us plateau; probes
//     TLP/fence/atomics/tile/phase/N-width all <=4%; request-halving
//     exhausted at LDS capacity: 16-col groups need 128KB W_hh).
//   out_gemm: R22 (M=128, N=80, grid 128x24) -- best measured (~155us).
//   prep_k: R23 fusion of cvt_z + cvt_wout + zero_hs_tail (one launch).
// Layout: 256 blocks = 128 col-groups x 2 slot-halves; group g owns 8 h-cols
// = 32 gate rows; 16B gather feeds 2 N-subtiles (8 MFMA/kt).
// hs2 [128][16384][2u64]; c_all 32B/slot block-private; ladder h-exchange
// (region_s at loff[s], write-once agent atomics, plain clamped gathers).
// ---------------------------------------------------------------------------

typedef float f4 __attribute__((ext_vector_type(4)));
typedef short s8 __attribute__((ext_vector_type(8)));
typedef unsigned short us8v __attribute__((ext_vector_type(8)));
typedef unsigned short us4v __attribute__((ext_vector_type(4)));
typedef unsigned long long u64;
typedef unsigned u32;

#define DEV __device__ __forceinline__

DEV unsigned short f2b(float f) {          // fp32 -> bf16 RNE
  unsigned u = __float_as_uint(f);
  return (unsigned short)((u + 0x7FFFu + ((u >> 16) & 1u)) >> 16);
}
DEV float b2f(unsigned short s) { return __uint_as_float(((unsigned)s) << 16); }

DEV f4 MFMA(s8 a, s8 b, f4 c) {
  return __builtin_amdgcn_mfma_f32_16x16x32_bf16(a, b, c, 0, 0, 0);
}
DEV s8 LD8(const unsigned short* p) { return *reinterpret_cast<const s8*>(p); }

DEV u32 AL32(const u32* p) {
  return __hip_atomic_load(p, __ATOMIC_RELAXED, __HIP_MEMORY_SCOPE_AGENT);
}
DEV void AS(u64* p, u64 v) {
  __hip_atomic_store(p, v, __ATOMIC_RELAXED, __HIP_MEMORY_SCOPE_AGENT);
}

DEV float sigf(float x) {
  float e = __builtin_amdgcn_exp2f(x * -1.44269504f);
  return __builtin_amdgcn_rcpf(1.f + e);
}
DEV float tanhf_fast(float x) {
  float e = __builtin_amdgcn_exp2f(x * 2.88539008f);
  return 1.f - 2.f * __builtin_amdgcn_rcpf(e + 1.f);
}

// ---- d_ws layout (bytes) ----
static constexpr size_t WS_GCNT = 0;
static constexpr size_t WS_NACT = 2048;
static constexpr size_t WS_HDR  = 4096;
static constexpr size_t WS_META = 4352;
static constexpr size_t WS_LOFF = 69888;
static constexpr size_t WS_TMP  = 131072;
static constexpr size_t WS_ZT   = 131072;
static constexpr size_t WS_WOUT = 4325376;
static constexpr size_t WS_HS2  = 8261632;  // hs2 [128][16384][2 u64] (32MB)
static constexpr size_t WS_END  = 41816064;
// ---- d_out scratch ----
static constexpr size_t DO_CALL = 35651584; // c_all [256][8192][4 u64]

// ---------------------------------------------------------------------------
// prep_k: fused cvt_z (blocks 0..2047), cvt_wout (2048..3969),
// zero_hs_tail (3970..4001).
__global__ void prep_k(const float* __restrict__ z, unsigned short* __restrict__ zt,
                       const float* __restrict__ W, unsigned short* __restrict__ wout16,
                       u64* __restrict__ hs2) {
  const int bid = blockIdx.x;
  const int tid = threadIdx.x;
  if (bid < 2048) {                       // z: 524288 float4 units exact
    int i = bid * 256 + tid;
    const float4 v = reinterpret_cast<const float4*>(z)[i];
    us4v u; u[0] = f2b(v.x); u[1] = f2b(v.y); u[2] = f2b(v.z); u[3] = f2b(v.w);
    reinterpret_cast<us4v*>(zt)[i] = u;
  } else if (bid < 3970) {                // wout: 491776 float4 units
    int i = (bid - 2048) * 256 + tid;
    if (i < 491776) {
      const float4 v = reinterpret_cast<const float4*>(W)[i];
      us4v u; u[0] = f2b(v.x); u[1] = f2b(v.y); u[2] = f2b(v.z); u[3] = f2b(v.w);
      reinterpret_cast<us4v*>(wout16)[i] = u;
    }
  } else {                                // hs2 tail rows 16352..16383
    int i = (bid - 3970) * 256 + tid;
    if (i < 8192) {
      int region = i >> 6, rr = (i & 63) >> 1, hf = i & 1;
      hs2[((size_t)region * 16384 + 16352 + rr) * 2 + hf] = 0ull;
    }
  }
}

// ---------------------------------------------------------------------------
__global__ __launch_bounds__(256) void seg_build_k(
    const int* __restrict__ dones, u32* __restrict__ tmp,
    u32* __restrict__ meta, u32* __restrict__ nact, u32* __restrict__ hdr,
    u32* __restrict__ loff) {
  __shared__ u32 hist[512];
  __shared__ u32 cur[512];
  __shared__ u32 scnt[32];
  const int tid = threadIdx.x;
  for (int i = tid; i < 512; i += 256) hist[i] = 0;
  __syncthreads();
  if (tid < 32) {
    int b = tid, cnt = 0, t0 = 0;
    for (int t = 1; t <= 511; ++t) {
      bool brk = (t == 511) || (dones[b * 512 + t - 1] != 0);
      if (brk) {
        int len = t - t0;
        tmp[b * 511 + cnt] = ((u32)t0 << 16) | (u32)len;
        atomicAdd(&hist[len], 1u);
        ++cnt; t0 = t;
      }
    }
    scnt[b] = (u32)cnt;
  }
  __syncthreads();
  if (tid == 0) {
    u32 acc = 0; int ml = 0;
    for (int L = 511; L >= 0; --L) {
      cur[L] = acc; nact[L] = acc;
      if (hist[L] && !ml) ml = L;
      acc += hist[L];
    }
    hdr[0] = acc; hdr[1] = (u32)ml;
    u32 off = 0; loff[0] = 0;
    for (int s2 = 1; s2 <= ml; ++s2) { loff[s2] = off; off += nact[s2]; }
  }
  __syncthreads();
  if (tid < 32) {
    int b = tid; u32 c = scnt[b];
    for (u32 i = 0; i < c; ++i) {
      u32 e = tmp[b * 511 + i];
      u32 len = e & 0xFFFFu, t0 = e >> 16;
      u32 slot = atomicAdd(&cur[len], 1u);
      meta[slot] = ((u32)b << 20) | (t0 << 10) | len;
    }
  }
}

// ---------------------------------------------------------------------------
// Segment-batched LSTM (R20/R22 verbatim). grid=256 = 128 col-groups x 2
// halves; block=512 (8 waves). Lane owns one slot (8 cols). 64-slot tiles.
__global__ __launch_bounds__(512, 1) void lstm_seg_k(
    const float* __restrict__ Whh, const float* __restrict__ Wih,
    const float* __restrict__ embed, const float* __restrict__ bih,
    const float* __restrict__ bhh, const int* __restrict__ actions,
    const unsigned short* __restrict__ zt, const u32* __restrict__ meta,
    const u32* __restrict__ nact, const u32* __restrict__ hdr,
    const u32* __restrict__ loff, u64* __restrict__ hsl,
    u64* __restrict__ c_all, u64* __restrict__ hs2,
    u32* __restrict__ gcnt) {
  const int blk = blockIdx.x;
  const int g = blk >> 1;                 // col-group 0..127
  const int half = blk & 1;               // slot-tile parity
  const int tid = threadIdx.x;
  const int lane = tid & 63;
  const int w = tid >> 6;                 // wave 0..7
  const int ln = lane & 15, lk = lane >> 4;

  __shared__ alignas(16) unsigned short whh_sw[32 * 2 * 64 * 8];  // 64 KB
  __shared__ alignas(16) unsigned short wz_sw[4 * 2 * 64 * 8];    // 8 KB
  __shared__ float abias[18][32];
  __shared__ float red[8][64][33];        // wave-private transpose 67.6KB

  for (int i = tid; i < 32768; i += 512) {
    int j = i & 7, L = (i >> 3) & 63, nt = (i >> 9) & 1, kt = i >> 10;
    int n = nt * 16 + (L & 15);           // packed gate idx 0..31
    int grow = (n >> 3) * 1024 + g * 8 + (n & 7);
    int k = kt * 32 + ((L >> 4) << 3) + j;
    whh_sw[i] = f2b(Whh[grow * 1024 + k]);
  }
  for (int i = tid; i < 4096; i += 512) {
    int j = i & 7, L = (i >> 3) & 63, nt = (i >> 9) & 1, kz = i >> 10;
    int n = nt * 16 + (L & 15);
    int grow = (n >> 3) * 1024 + g * 8 + (n & 7);
    int k = kz * 32 + ((L >> 4) << 3) + j;
    wz_sw[i] = f2b(Wih[grow * 144 + k]);
  }
  for (int i = tid; i < 18 * 32; i += 512) {
    int a = i >> 5, n = i & 31;
    int grow = (n >> 3) * 1024 + g * 8 + (n & 7);
    float s = bih[grow] + bhh[grow];
    for (int j = 0; j < 16; ++j) s += embed[a * 16 + j] * Wih[grow * 144 + 128 + j];
    abias[a][n] = s;
  }
  __syncthreads();

  const int maxlen = (int)hdr[1];

  for (int s = 0; s < maxlen; ++s) {
    const u32 N = nact[s];
    const int ntiles = (int)((N + 63) >> 6);
    const u64* hread = hsl + (size_t)loff[s] * 256;
    u64* hwrite = hsl + (size_t)loff[s + 1] * 256;

    for (int tile = half + 2 * w; tile < ntiles; tile += 16) {
      const u32 sb = (u32)tile << 6;
      const u32 slot = sb + (u32)lane;
      const bool valid = slot < N;
      const u32 m = valid ? meta[slot] : 0u;
      const u32 b = m >> 20, t0 = (m >> 10) & 1023u, L = m & 1023u;
      const int zrow = (int)(b * 512u + t0 + (u32)s);
      const int orow = (int)(b * 511u + t0 + (u32)s);
      const u32 act = valid ? (u32)actions[zrow] : 0u;
      u64 cq[4] = {0, 0, 0, 0};
      if (s && valid) {
        const u64* cp = c_all + ((size_t)blk << 15) + ((size_t)slot << 2);
        cq[0] = cp[0]; cq[1] = cp[1]; cq[2] = cp[2]; cq[3] = cp[3];
      }
      int zr[4];
#pragma unroll
      for (int q = 0; q < 4; ++q) zr[q] = __shfl(zrow, ln + 16 * q, 64);

      f4 a00 = {0,0,0,0}, a01 = {0,0,0,0}, a10 = {0,0,0,0}, a11 = {0,0,0,0};
      f4 a20 = {0,0,0,0}, a21 = {0,0,0,0}, a30 = {0,0,0,0}, a31 = {0,0,0,0};
#pragma unroll
      for (int kz = 0; kz < 4; ++kz) {     // z contribution (K=128)
        s8 b0 = LD8(wz_sw + (((kz * 2 + 0) * 64 + lane) << 3));
        s8 b1 = LD8(wz_sw + (((kz * 2 + 1) * 64 + lane) << 3));
        s8 f0 = LD8(zt + (size_t)zr[0] * 128 + kz * 32 + (lk << 3));
        s8 f1 = LD8(zt + (size_t)zr[1] * 128 + kz * 32 + (lk << 3));
        s8 f2 = LD8(zt + (size_t)zr[2] * 128 + kz * 32 + (lk << 3));
        s8 f3 = LD8(zt + (size_t)zr[3] * 128 + kz * 32 + (lk << 3));
        a00 = MFMA(f0, b0, a00);  a01 = MFMA(f0, b1, a01);
        a10 = MFMA(f1, b0, a10);  a11 = MFMA(f1, b1, a11);
        a20 = MFMA(f2, b0, a20);  a21 = MFMA(f2, b1, a21);
        a30 = MFMA(f3, b0, a30);  a31 = MFMA(f3, b1, a31);
      }
      if (s) {  // h gather: plain coalesced 16B loads, clamped inside region
        const u32 r0c = (sb + (u32)ln      < N) ? sb + (u32)ln      : N - 1u;
        const u32 r1c = (sb + (u32)ln + 16 < N) ? sb + (u32)ln + 16 : N - 1u;
        const u32 r2c = (sb + (u32)ln + 32 < N) ? sb + (u32)ln + 32 : N - 1u;
        const u32 r3c = (sb + (u32)ln + 48 < N) ? sb + (u32)ln + 48 : N - 1u;
        const unsigned short* h0 =
            (const unsigned short*)(hread + (size_t)r0c * 256) + (lk << 3);
        const unsigned short* h1 =
            (const unsigned short*)(hread + (size_t)r1c * 256) + (lk << 3);
        const unsigned short* h2 =
            (const unsigned short*)(hread + (size_t)r2c * 256) + (lk << 3);
        const unsigned short* h3 =
            (const unsigned short*)(hread + (size_t)r3c * 256) + (lk << 3);
#pragma unroll 8
        for (int kt = 0; kt < 32; ++kt) {
          s8 b0 = LD8(whh_sw + (((kt * 2 + 0) * 64 + lane) << 3));
          s8 b1 = LD8(whh_sw + (((kt * 2 + 1) * 64 + lane) << 3));
          s8 f0 = LD8(h0 + (kt << 5));
          s8 f1 = LD8(h1 + (kt << 5));
          s8 f2 = LD8(h2 + (kt << 5));
          s8 f3 = LD8(h3 + (kt << 5));
          a00 = MFMA(f0, b0, a00);  a01 = MFMA(f0, b1, a01);
          a10 = MFMA(f1, b0, a10);  a11 = MFMA(f1, b1, a11);
          a20 = MFMA(f2, b0, a20);  a21 = MFMA(f2, b1, a21);
          a30 = MFMA(f3, b0, a30);  a31 = MFMA(f3, b1, a31);
        }
      }

      // transpose: D row = 16q + 4lk + j, col = nt*16 + ln
#pragma unroll
      for (int j = 0; j < 4; ++j) {
        red[w][(lk << 2) + j][ln]           = a00[j];
        red[w][(lk << 2) + j][16 + ln]      = a01[j];
        red[w][16 + (lk << 2) + j][ln]      = a10[j];
        red[w][16 + (lk << 2) + j][16 + ln] = a11[j];
        red[w][32 + (lk << 2) + j][ln]      = a20[j];
        red[w][32 + (lk << 2) + j][16 + ln] = a21[j];
        red[w][48 + (lk << 2) + j][ln]      = a30[j];
        red[w][48 + (lk << 2) + j][16 + ln] = a31[j];
      }
      // same-wave DS ordering
      const bool carry = valid && (L > (u32)(s + 1));
      u32 cb[8]; unsigned short hb[8];
#pragma unroll
      for (int e = 0; e < 8; ++e) {   // lane's slot, cols 0..7
        float gi = red[w][lane][e]      + abias[act][e];
        float gf = red[w][lane][8 + e]  + abias[act][8 + e];
        float gg = red[w][lane][16 + e] + abias[act][16 + e];
        float go = red[w][lane][24 + e] + abias[act][24 + e];
        const u32 cpb = (e & 1) ? (u32)(cq[e >> 1] >> 32) : (u32)cq[e >> 1];
        const float cprev = __uint_as_float(cpb);
        const float si = sigf(gi), sf = sigf(gf), so = sigf(go);
        const float cn = sf * cprev + si * tanhf_fast(gg);
        const float hn = so * tanhf_fast(cn);
        cb[e] = __float_as_uint(cn);
        hb[e] = f2b(hn);
      }
      if (carry) {   // c carry: 32B plain store
        u64* cp = c_all + ((size_t)blk << 15) + ((size_t)slot << 2);
        cp[0] = ((u64)cb[1] << 32) | (u64)cb[0];
        cp[1] = ((u64)cb[3] << 32) | (u64)cb[2];
        cp[2] = ((u64)cb[5] << 32) | (u64)cb[4];
        cp[3] = ((u64)cb[7] << 32) | (u64)cb[6];
      }
      const u64 hu0 = (u64)hb[0] | ((u64)hb[1] << 16) |
                      ((u64)hb[2] << 32) | ((u64)hb[3] << 48);
      const u64 hu1 = (u64)hb[4] | ((u64)hb[5] << 16) |
                      ((u64)hb[6] << 32) | ((u64)hb[7] << 48);
      if (valid) {
        u64* hp = hs2 + ((size_t)g * 16384 + orow) * 2;
        hp[0] = hu0; hp[1] = hu1;                      // history (plain)
        if (carry) {                                   // carry h (atomic)
          AS(hwrite + (size_t)slot * 256 + 2 * g, hu0);
          AS(hwrite + (size_t)slot * 256 + 2 * g + 1, hu1);
        }
      }
    }

    // per-wave drain, block sync, global barrier
    asm volatile("s_waitcnt vmcnt(0)" ::: "memory");
    __syncthreads();
    if (s + 1 < maxlen) {
      if (tid == 0) {
        __hip_atomic_fetch_add(gcnt + (blk >> 4) * 32, 1u,
                               __ATOMIC_RELAXED, __HIP_MEMORY_SCOPE_AGENT);
        const u32 tgt = (u32)(s + 1) * 16u;
        for (u32 spin = 0; spin < (1u << 20); ++spin) {
          u32 mn = 0xFFFFFFFFu;
#pragma unroll
          for (int gg2 = 0; gg2 < 16; ++gg2) {
            u32 v = AL32(gcnt + gg2 * 32);
            mn = (v < mn) ? v : mn;
          }
          if (mn >= tgt) break;
          __builtin_amdgcn_s_sleep(1);
        }
      }
      __syncthreads();
    }
  }
}

// ---------------------------------------------------------------------------
// out = hs @ W_out^T (+bias), fused logsumexp on logmix; nblk==23 also
// computes done_p (W_out row 1920). R22 config: M=128 (grid 128x24).
__global__ __launch_bounds__(256, 2) void out_gemm_k(
    const u64* __restrict__ hs2, const unsigned short* __restrict__ wout,
    const float* __restrict__ b_out, float* __restrict__ out) {
  const int mblk = blockIdx.x, nblk = blockIdx.y;
  const int tid = threadIdx.x, lane = tid & 63, w = tid >> 6;
  const int ln = lane & 15, lk = lane >> 4;
  __shared__ alignas(16) unsigned char smraw[43520];
  unsigned short* bsm = (unsigned short*)smraw;  // [96][136] bf16 B-chunk
  float* ep = (float*)smraw;                     // [128][84] f32 lse tile
  const bool last = (nblk == 23);

  if (last) {  // zero pad rows 81..95 (cols 1921+ of the 6th subtile)
    for (int i = tid; i < 15 * 136; i += 256) bsm[81 * 136 + i] = 0;
  }
  __syncthreads();

  const int r0 = mblk * 128 + w * 16;    // lower subtile; upper = r0+64
  f4 accA[5], accB[5];
#pragma unroll
  for (int s = 0; s < 5; ++s) {
    accA[s] = (f4){0.f, 0.f, 0.f, 0.f};
    accB[s] = (f4){0.f, 0.f, 0.f, 0.f};
  }
  f4 acc5A = {0.f, 0.f, 0.f, 0.f}, acc5B = {0.f, 0.f, 0.f, 0.f};

  for (int kc = 0; kc < 8; ++kc) {  // K chunks of 128
#pragma unroll
    for (int ii = 0; ii < 5; ++ii) {           // 1280 us8 chunks exact
      int i = tid + ii * 256;
      int n = i >> 4, k16 = i & 15;
      us8v v = *reinterpret_cast<const us8v*>(
          wout + (size_t)(nblk * 80 + n) * 1024 + kc * 128 + (k16 << 3));
      *reinterpret_cast<us8v*>(bsm + n * 136 + (k16 << 3)) = v;
    }
    if (last && tid < 16) {                    // row 80 = wout row 1920
      us8v v = *reinterpret_cast<const us8v*>(
          wout + (size_t)1920 * 1024 + kc * 128 + (tid << 3));
      *reinterpret_cast<us8v*>(bsm + 80 * 136 + (tid << 3)) = v;
    }
    __syncthreads();
#pragma unroll
    for (int ks = 0; ks < 4; ++ks) {
      const int k0 = kc * 128 + ks * 32 + (lk << 3);
      s8 aLo = *reinterpret_cast<const s8*>(
          hs2 + ((size_t)(k0 >> 3) * 16384 + r0 + ln) * 2);
      s8 aHi = *reinterpret_cast<const s8*>(
          hs2 + ((size_t)(k0 >> 3) * 16384 + r0 + 64 + ln) * 2);
#pragma unroll
      for (int s = 0; s < 5; ++s) {
        s8 b = LD8(bsm + (s * 16 + ln) * 136 + ks * 32 + (lk << 3));
        accA[s] = MFMA(aLo, b, accA[s]);
        accB[s] = MFMA(aHi, b, accB[s]);
      }
      if (last) {
        s8 b6 = LD8(bsm + ((80 + ln) * 136) + ks * 32 + (lk << 3));
        acc5A = MFMA(aLo, b6, acc5A);
        acc5B = MFMA(aHi, b6, acc5B);
      }
    }
    __syncthreads();
  }

  const int T = nblk >> 3;  // 0 logmix, 1 mu, 2 logstd
  if (T) {
    float* base = out + (size_t)10465280 * T;
    const int lc0 = (nblk - (T << 3)) * 80;
#pragma unroll
    for (int s = 0; s < 5; ++s) {
      const int lc = lc0 + s * 16 + ln;
      const float bias = b_out[T * 640 + lc];
#pragma unroll
      for (int j = 0; j < 4; ++j) {
        const int rowA = r0 + (lk << 2) + j;
        const int rowB = rowA + 64;
        if (rowA < 16352) base[(size_t)rowA * 640 + lc] = accA[s][j] + bias;
        if (rowB < 16352) base[(size_t)rowB * 640 + lc] = accB[s][j] + bias;
      }
    }
    if (last && ln == 0) {     // done_p: col 0 of the 6th subtile
      const float bias = b_out[1920];
#pragma unroll
      for (int j = 0; j < 4; ++j) {
        const int rowA = r0 + (lk << 2) + j;
        const int rowB = rowA + 64;
        if (rowA < 16352) out[31395840 + rowA] = acc5A[j] + bias;
        if (rowB < 16352) out[31395840 + rowB] = acc5B[j] + bias;
      }
    }
  } else {  // logmix: LDS bounce + per-(row, z-group) logsumexp over 5
#pragma unroll
    for (int s = 0; s < 5; ++s) {
      const float bias = b_out[nblk * 80 + s * 16 + ln];
#pragma unroll
      for (int j = 0; j < 4; ++j) {
        ep[(w * 16 + (lk << 2) + j) * 84 + s * 16 + ln]        = accA[s][j] + bias;
        ep[(64 + w * 16 + (lk << 2) + j) * 84 + s * 16 + ln]   = accB[s][j] + bias;
      }
    }
    __syncthreads();
    for (int task = tid; task < 2048; task += 256) {
      const int rr = task >> 4, grp = task & 15;
      const int row = mblk * 128 + rr;
      const float* e = ep + rr * 84 + grp * 5;
      float v0 = e[0], v1 = e[1], v2 = e[2], v3 = e[3], v4 = e[4];
      float mx = fmaxf(fmaxf(fmaxf(v0, v1), fmaxf(v2, v3)), v4);
      float ssum = expf(v0 - mx) + expf(v1 - mx) + expf(v2 - mx) +
                   expf(v3 - mx) + expf(v4 - mx);
      float lse = mx + logf(ssum);
      if (row < 16352) {
        float* o = out + (size_t)row * 640 + nblk * 80 + grp * 5;
        o[0] = v0 - lse; o[1] = v1 - lse; o[2] = v2 - lse;
        o[3] = v3 - lse; o[4] = v4 - lse;
      }
    }
  }
}

// ---------------------------------------------------------------------------
extern "C" void kernel_launch(void* const* d_in, const int* in_sizes, int n_in,
                              void* d_out, int out_size, void* d_ws, size_t ws_size,
                              hipStream_t stream) {
  const float* z       = (const float*)d_in[0];
  const int*   actions = (const int*)d_in[1];
  const int*   dones   = (const int*)d_in[2];
  const float* embed   = (const float*)d_in[3];
  const float* Wih     = (const float*)d_in[4];
  const float* Whh     = (const float*)d_in[5];
  const float* bih     = (const float*)d_in[6];
  const float* bhh     = (const float*)d_in[7];
  const float* Wout    = (const float*)d_in[8];
  const float* bout    = (const float*)d_in[9];
  float* out = (float*)d_out;

  if (ws_size < WS_END) return;

  char* ws = (char*)d_ws;
  u32* gcnt              = (u32*)(ws + WS_GCNT);
  u32* nact              = (u32*)(ws + WS_NACT);
  u32* hdr               = (u32*)(ws + WS_HDR);
  u32* metaA             = (u32*)(ws + WS_META);
  u32* loff              = (u32*)(ws + WS_LOFF);
  u32* tmp               = (u32*)(ws + WS_TMP);
  unsigned short* zt     = (unsigned short*)(ws + WS_ZT);
  unsigned short* wout16 = (unsigned short*)(ws + WS_WOUT);
  u64* hs2               = (u64*)(ws + WS_HS2);
  u64* hsl   = (u64*)d_out;                          // ladder <= 33.4MB
  u64* call  = (u64*)((char*)d_out + DO_CALL);       // 64MB c-state

  hipMemsetAsync(d_ws, 0, 2048, stream);  // barrier counters only

  seg_build_k<<<1, 256, 0, stream>>>(dones, tmp, metaA, nact, hdr, loff);
  prep_k<<<4002, 256, 0, stream>>>(z, zt, Wout, wout16, hs2);
  lstm_seg_k<<<256, 512, 0, stream>>>(Whh, Wih, embed, bih, bhh, actions,
                                      zt, metaA, nact, hdr, loff, hsl, call,
                                      hs2, gcnt);
  out_gemm_k<<<dim3(128, 24), 256, 0, stream>>>(hs2, wout16, bout, out);
}